// Round 15
// baseline (32.677 us; speedup 1.0000x reference)
//
#include <hip/hip_runtime.h>

#define EMBED 256
#define ITERS 2

typedef _Float16 h2v __attribute__((ext_vector_type(2)));
typedef float f4v __attribute__((ext_vector_type(4)));

__device__ inline float rfl(float v) {
    return __uint_as_float(__builtin_amdgcn_readfirstlane(__float_as_uint(v)));
}
template<int CTRL>
__device__ inline float dppf(float v) {
    return __int_as_float(__builtin_amdgcn_mov_dpp(__float_as_int(v), CTRL, 0xf, 0xf, true));
}
__device__ inline float2 unpk2(int u) {
    h2v h = __builtin_bit_cast(h2v, u);
    return make_float2((float)h.x, (float)h.y);
}
__device__ inline int pk2(float a, float b) {
    return __builtin_bit_cast(int, __builtin_amdgcn_cvt_pkrtz(a, b));
}
__device__ inline void lds_fence() {
    asm volatile("s_waitcnt lgkmcnt(0)" ::: "memory");
}
__device__ inline void nt_store4(float* p, float a, float b, float c, float d) {
    f4v v = {a, b, c, d};
    __builtin_nontemporal_store(v, (f4v*)p);
}

// ---- analytic-z compile-time term table (R7 derivation) ----
constexpr unsigned MQ[8] = {0x03,0x06,0x0C,0x18,0x30,0x60,0xC0,0x83};
constexpr unsigned TQ[8] = {0xAB,0xFD,0xFA,0xF5,0xEA,0xD5,0xAA,0x55};
constexpr unsigned AQ[8] = {0xFE,0x03,0x07,0x0F,0x1F,0x3F,0x7F,0xFF};

constexpr int popc8(unsigned x) {
    int c = 0;
    for (int i = 0; i < 8; ++i) c += (x >> i) & 1;
    return c;
}
struct Term { int q; unsigned S; unsigned M; float sgn; };
struct TermTab { Term t[64]; int n; };
constexpr TermTab make_terms() {
    TermTab tt{};
    int n = 0;
    for (int q = 0; q < 8; ++q)
        for (unsigned S = 0; S < 256; ++S) {
            if ((S & ~AQ[q]) != 0) continue;
            unsigned M = 0;
            for (int j = 0; j < 8; ++j) if ((S >> j) & 1) M ^= MQ[j];
            if ((M & ~TQ[q]) != 0) continue;
            const int tot = popc8(S) + popc8(M);   // always even
            tt.t[n].q = q; tt.t[n].S = S; tt.t[n].M = M;
            tt.t[n].sgn = ((tot >> 1) & 1) ? -1.0f : 1.0f;
            ++n;
        }
    tt.n = n;
    return tt;
}
constexpr TermTab TT = make_terms();
static_assert(TT.n == 60, "term count");

// Wave-independent fused kernel; each wave owns ITERS groups of 8 samples.
// No __syncthreads; per-wave LDS scratch (double-buffered per iteration).
__global__ __launch_bounds__(256) void fused_kernel(
    const float* __restrict__ x,    // (65536, 256)
    const float* __restrict__ W1,   // (8, 256)
    const float* __restrict__ b1,   // (8,)
    const float* __restrict__ qw,   // (2, 8)
    const float* __restrict__ W2,   // (256, 8)
    const float* __restrict__ b2,   // (256,)
    float* __restrict__ out)        // (65536, 256)
{
    const int tid  = threadIdx.x;
    const int lane = tid & 63;
    const int w    = tid >> 6;
    const int wid  = blockIdx.x * 4 + w;     // 0..4095

    __shared__ alignas(16) int   hcs[4][ITERS][64];
    __shared__ alignas(16) float zf[4][ITERS][64];

    // ---- phase-A constants ----
    float4 w1c[8];
#pragma unroll
    for (int q = 0; q < 8; ++q)
        w1c[q] = *(const float4*)(W1 + q * EMBED + 4 * lane);
    const int aq = (lane >> 1) & 7;            // valid for lane<16
    const float b1f = b1[aq] + qw[aq];         // + layer-1 RX angle (angles add)

    // gate trig (layer 2) for phase B
    float qc[8], qs[8];
#pragma unroll
    for (int j = 0; j < 8; ++j) {
        const float ph = qw[8 + j];
        qc[j] = rfl(__cosf(ph));
        qs[j] = rfl(__sinf(ph));
    }

    const bool s0 = lane & 1, s1 = lane & 2, s2 = lane & 4, s3 = lane & 8;

#pragma unroll
    for (int it = 0; it < ITERS; ++it) {
        const int grp = wid * ITERS + it;      // 8-sample group, 0..8191

        // ---- phase A: theta = x.W1^T + b1 + qw[0]; pack (cos,sin) to LDS ----
#pragma unroll 2
        for (int step = 0; step < 4; ++step) {
            const int p = grp * 4 + step;      // pair index; samples 2p, 2p+1
            const float4 x0 = *(const float4*)(x + (size_t)p * 512 + 4 * lane);
            const float4 x1 = *(const float4*)(x + (size_t)p * 512 + 256 + 4 * lane);

            float vv[16];
#pragma unroll
            for (int q = 0; q < 8; ++q) {
                vv[2*q]   = x0.x*w1c[q].x + x0.y*w1c[q].y + x0.z*w1c[q].z + x0.w*w1c[q].w;
                vv[2*q+1] = x1.x*w1c[q].x + x1.y*w1c[q].y + x1.z*w1c[q].z + x1.w*w1c[q].w;
            }
#pragma unroll
            for (int i = 0; i < 8; ++i) {   // m=1 (DPP)
                float a = vv[2*i], b = vv[2*i+1];
                float keep = s0 ? b : a, send = s0 ? a : b;
                vv[i] = keep + dppf<0xB1>(send);
            }
#pragma unroll
            for (int i = 0; i < 4; ++i) {   // m=2 (DPP)
                float a = vv[2*i], b = vv[2*i+1];
                float keep = s1 ? b : a, send = s1 ? a : b;
                vv[i] = keep + dppf<0x4E>(send);
            }
#pragma unroll
            for (int i = 0; i < 2; ++i) {   // m=4
                float a = vv[2*i], b = vv[2*i+1];
                float keep = s2 ? b : a, send = s2 ? a : b;
                vv[i] = keep + __shfl_xor(send, 4, 64);
            }
            {                               // m=8
                float a = vv[0], b = vv[1];
                float keep = s3 ? b : a, send = s3 ? a : b;
                vv[0] = keep + __shfl_xor(send, 8, 64);
            }
            float r = vv[0];
            r += __shfl_xor(r, 16, 64);
            r += __shfl_xor(r, 32, 64);     // lane<16: dot for (q=lane>>1, par=lane&1)

            const float th = r + b1f;
            const int pk = pk2(__cosf(th), __sinf(th));
            if (lane < 16)
                hcs[w][it][(2 * step + (lane & 1)) * 8 + (lane >> 1)] = pk;
        }
        lds_fence();

        // ---- phase B: lane (sl,q) accumulates q's terms for sample sl ----
        const int sl = lane >> 3;
        const int q  = lane & 7;
        const int4 ua = *(const int4*)&hcs[w][it][sl * 8];
        const int4 ub = *(const int4*)&hcs[w][it][sl * 8 + 4];
        float u[8], v[8];
#define UNPK(U, Q) do { float2 f = unpk2(U); u[Q] = f.x; v[Q] = f.y; } while (0)
        UNPK(ua.x, 0); UNPK(ua.y, 1); UNPK(ua.z, 2); UNPK(ua.w, 3);
        UNPK(ub.x, 4); UNPK(ub.y, 5); UNPK(ub.z, 6); UNPK(ub.w, 7);
#undef UNPK

        float acc = 0.0f, psum = 0.0f;
#pragma unroll
        for (int t = 0; t < 60; ++t) {
            const int qt = TT.t[t].q;
            const unsigned S = TT.t[t].S, M = TT.t[t].M;
            float c = TT.t[t].sgn;
#pragma unroll
            for (int j = 0; j < 8; ++j)
                if ((AQ[qt] >> j) & 1) c *= ((S >> j) & 1) ? qs[j] : qc[j];
#pragma unroll
            for (int i = 0; i < 8; ++i)
                if ((TQ[qt] >> i) & 1) c *= ((M >> i) & 1) ? v[i] : u[i];
            psum += c;
            const bool qend = (t == 59) || (TT.t[t + 1].q != qt);
            if (qend) { acc += (q == qt) ? psum : 0.0f; psum = 0.0f; }
        }
        zf[w][it][lane] = acc;
        lds_fence();

        // ---- phase C: out = z.W2^T + b2, 8 coalesced rows per wave ----
        float4 w2f[8];
#pragma unroll
        for (int j = 0; j < 8; ++j)
            w2f[j] = *(const float4*)(W2 + (size_t)lane * 32 + 4 * j);
        const float4 b2c = *(const float4*)(b2 + 4 * lane);

        float* orow = out + (size_t)(grp * 8) * EMBED + 4 * lane;
#pragma unroll
        for (int r = 0; r < 8; ++r) {
            const float4 za = *(const float4*)&zf[w][it][r * 8];
            const float4 zb = *(const float4*)&zf[w][it][r * 8 + 4];
            const float zq[8] = {za.x, za.y, za.z, za.w, zb.x, zb.y, zb.z, zb.w};
            float o0 = b2c.x, o1 = b2c.y, o2 = b2c.z, o3 = b2c.w;
#pragma unroll
            for (int k = 0; k < 8; ++k) {
                const float* f0 = (const float*)&w2f[0 + (k >> 2)];
                const float* f1 = (const float*)&w2f[2 + (k >> 2)];
                const float* f2 = (const float*)&w2f[4 + (k >> 2)];
                const float* f3 = (const float*)&w2f[6 + (k >> 2)];
                o0 += zq[k] * f0[k & 3]; o1 += zq[k] * f1[k & 3];
                o2 += zq[k] * f2[k & 3]; o3 += zq[k] * f3[k & 3];
            }
            nt_store4(orow + (size_t)r * EMBED, o0, o1, o2, o3);
        }
    }
}

extern "C" void kernel_launch(void* const* d_in, const int* in_sizes, int n_in,
                              void* d_out, int out_size, void* d_ws, size_t ws_size,
                              hipStream_t stream) {
    const float* x  = (const float*)d_in[0];
    const float* W1 = (const float*)d_in[1];
    const float* b1 = (const float*)d_in[2];
    const float* qw = (const float*)d_in[3];
    const float* W2 = (const float*)d_in[4];
    const float* b2 = (const float*)d_in[5];
    float* out = (float*)d_out;

    hipLaunchKernelGGL(fused_kernel, dim3(65536 / (8 * ITERS) / 4), dim3(256),
                       0, stream, x, W1, b1, qw, W2, b2, out);
}

// Round 16
// 32.328 us; speedup vs baseline: 1.0108x; 1.0108x over previous
//
#include <hip/hip_runtime.h>

#define EMBED 256
#define ITERS 2

typedef _Float16 h2v __attribute__((ext_vector_type(2)));
typedef float f4v __attribute__((ext_vector_type(4)));

__device__ inline float rfl(float v) {
    return __uint_as_float(__builtin_amdgcn_readfirstlane(__float_as_uint(v)));
}
template<int CTRL>
__device__ inline float dppf(float v) {
    return __int_as_float(__builtin_amdgcn_mov_dpp(__float_as_int(v), CTRL, 0xf, 0xf, true));
}
__device__ inline float2 unpk2(int u) {
    h2v h = __builtin_bit_cast(h2v, u);
    return make_float2((float)h.x, (float)h.y);
}
__device__ inline int pk2(float a, float b) {
    return __builtin_bit_cast(int, __builtin_amdgcn_cvt_pkrtz(a, b));
}
__device__ inline void lds_fence() {
    asm volatile("s_waitcnt lgkmcnt(0)" ::: "memory");
}
__device__ inline void nt_store4(float* p, float a, float b, float c, float d) {
    f4v v = {a, b, c, d};
    __builtin_nontemporal_store(v, (f4v*)p);
}

// ---- analytic-z compile-time term table (R7 derivation) ----
constexpr unsigned MQ[8] = {0x03,0x06,0x0C,0x18,0x30,0x60,0xC0,0x83};
constexpr unsigned TQ[8] = {0xAB,0xFD,0xFA,0xF5,0xEA,0xD5,0xAA,0x55};
constexpr unsigned AQ[8] = {0xFE,0x03,0x07,0x0F,0x1F,0x3F,0x7F,0xFF};

constexpr int popc8(unsigned x) {
    int c = 0;
    for (int i = 0; i < 8; ++i) c += (x >> i) & 1;
    return c;
}
struct Term { int q; unsigned S; unsigned M; float sgn; };
struct TermTab { Term t[64]; int n; };
constexpr TermTab make_terms() {
    TermTab tt{};
    int n = 0;
    for (int q = 0; q < 8; ++q)
        for (unsigned S = 0; S < 256; ++S) {
            if ((S & ~AQ[q]) != 0) continue;
            unsigned M = 0;
            for (int j = 0; j < 8; ++j) if ((S >> j) & 1) M ^= MQ[j];
            if ((M & ~TQ[q]) != 0) continue;
            const int tot = popc8(S) + popc8(M);   // always even
            tt.t[n].q = q; tt.t[n].S = S; tt.t[n].M = M;
            tt.t[n].sgn = ((tot >> 1) & 1) ? -1.0f : 1.0f;
            ++n;
        }
    tt.n = n;
    return tt;
}
constexpr TermTab TT = make_terms();
static_assert(TT.n == 60, "term count");

// Wave-independent fused kernel; each wave owns ITERS groups of 8 samples,
// processed in a NON-unrolled loop (keeps VGPR below the 64 occupancy cliff).
// No __syncthreads; per-wave LDS scratch; same-wave DS ordering via lgkmcnt.
__global__ __launch_bounds__(256) void fused_kernel(
    const float* __restrict__ x,    // (65536, 256)
    const float* __restrict__ W1,   // (8, 256)
    const float* __restrict__ b1,   // (8,)
    const float* __restrict__ qw,   // (2, 8)
    const float* __restrict__ W2,   // (256, 8)
    const float* __restrict__ b2,   // (256,)
    float* __restrict__ out)        // (65536, 256)
{
    const int tid  = threadIdx.x;
    const int lane = tid & 63;
    const int w    = tid >> 6;
    const int wid  = blockIdx.x * 4 + w;     // 0..4095

    __shared__ alignas(16) int   hcs[4][64];
    __shared__ alignas(16) float zf[4][64];

    // ---- phase-A constants ----
    float4 w1c[8];
#pragma unroll
    for (int q = 0; q < 8; ++q)
        w1c[q] = *(const float4*)(W1 + q * EMBED + 4 * lane);
    const int aq = (lane >> 1) & 7;            // valid for lane<16
    const float b1f = b1[aq] + qw[aq];         // + layer-1 RX angle (angles add)

    // gate trig (layer 2) for phase B
    float qc[8], qs[8];
#pragma unroll
    for (int j = 0; j < 8; ++j) {
        const float ph = qw[8 + j];
        qc[j] = rfl(__cosf(ph));
        qs[j] = rfl(__sinf(ph));
    }

    const bool s0 = lane & 1, s1 = lane & 2, s2 = lane & 4, s3 = lane & 8;

#pragma unroll 1
    for (int it = 0; it < ITERS; ++it) {
        const int grp = wid * ITERS + it;      // 8-sample group, 0..8191

        // ---- phase A: theta = x.W1^T + b1 + qw[0]; pack (cos,sin) to LDS ----
#pragma unroll 2
        for (int step = 0; step < 4; ++step) {
            const int p = grp * 4 + step;      // pair index; samples 2p, 2p+1
            const float4 x0 = *(const float4*)(x + (size_t)p * 512 + 4 * lane);
            const float4 x1 = *(const float4*)(x + (size_t)p * 512 + 256 + 4 * lane);

            float vv[16];
#pragma unroll
            for (int q = 0; q < 8; ++q) {
                vv[2*q]   = x0.x*w1c[q].x + x0.y*w1c[q].y + x0.z*w1c[q].z + x0.w*w1c[q].w;
                vv[2*q+1] = x1.x*w1c[q].x + x1.y*w1c[q].y + x1.z*w1c[q].z + x1.w*w1c[q].w;
            }
#pragma unroll
            for (int i = 0; i < 8; ++i) {   // m=1 (DPP)
                float a = vv[2*i], b = vv[2*i+1];
                float keep = s0 ? b : a, send = s0 ? a : b;
                vv[i] = keep + dppf<0xB1>(send);
            }
#pragma unroll
            for (int i = 0; i < 4; ++i) {   // m=2 (DPP)
                float a = vv[2*i], b = vv[2*i+1];
                float keep = s1 ? b : a, send = s1 ? a : b;
                vv[i] = keep + dppf<0x4E>(send);
            }
#pragma unroll
            for (int i = 0; i < 2; ++i) {   // m=4
                float a = vv[2*i], b = vv[2*i+1];
                float keep = s2 ? b : a, send = s2 ? a : b;
                vv[i] = keep + __shfl_xor(send, 4, 64);
            }
            {                               // m=8
                float a = vv[0], b = vv[1];
                float keep = s3 ? b : a, send = s3 ? a : b;
                vv[0] = keep + __shfl_xor(send, 8, 64);
            }
            float r = vv[0];
            r += __shfl_xor(r, 16, 64);
            r += __shfl_xor(r, 32, 64);     // lane<16: dot for (q=lane>>1, par=lane&1)

            const float th = r + b1f;
            const int pk = pk2(__cosf(th), __sinf(th));
            if (lane < 16)
                hcs[w][(2 * step + (lane & 1)) * 8 + (lane >> 1)] = pk;
        }
        lds_fence();

        // ---- phase B: lane (sl,q) accumulates q's terms for sample sl ----
        const int sl = lane >> 3;
        const int q  = lane & 7;
        const int4 ua = *(const int4*)&hcs[w][sl * 8];
        const int4 ub = *(const int4*)&hcs[w][sl * 8 + 4];
        float u[8], v[8];
#define UNPK(U, Q) do { float2 f = unpk2(U); u[Q] = f.x; v[Q] = f.y; } while (0)
        UNPK(ua.x, 0); UNPK(ua.y, 1); UNPK(ua.z, 2); UNPK(ua.w, 3);
        UNPK(ub.x, 4); UNPK(ub.y, 5); UNPK(ub.z, 6); UNPK(ub.w, 7);
#undef UNPK

        float acc = 0.0f, psum = 0.0f;
#pragma unroll
        for (int t = 0; t < 60; ++t) {
            const int qt = TT.t[t].q;
            const unsigned S = TT.t[t].S, M = TT.t[t].M;
            float c = TT.t[t].sgn;
#pragma unroll
            for (int j = 0; j < 8; ++j)
                if ((AQ[qt] >> j) & 1) c *= ((S >> j) & 1) ? qs[j] : qc[j];
#pragma unroll
            for (int i = 0; i < 8; ++i)
                if ((TQ[qt] >> i) & 1) c *= ((M >> i) & 1) ? v[i] : u[i];
            psum += c;
            const bool qend = (t == 59) || (TT.t[t + 1].q != qt);
            if (qend) { acc += (q == qt) ? psum : 0.0f; psum = 0.0f; }
        }
        zf[w][lane] = acc;
        lds_fence();

        // ---- phase C: out = z.W2^T + b2, 8 coalesced rows per wave ----
        float4 w2f[8];
#pragma unroll
        for (int j = 0; j < 8; ++j)
            w2f[j] = *(const float4*)(W2 + (size_t)lane * 32 + 4 * j);
        const float4 b2c = *(const float4*)(b2 + 4 * lane);

        float* orow = out + (size_t)(grp * 8) * EMBED + 4 * lane;
#pragma unroll
        for (int r = 0; r < 8; ++r) {
            const float4 za = *(const float4*)&zf[w][r * 8];
            const float4 zb = *(const float4*)&zf[w][r * 8 + 4];
            const float zq[8] = {za.x, za.y, za.z, za.w, zb.x, zb.y, zb.z, zb.w};
            float o0 = b2c.x, o1 = b2c.y, o2 = b2c.z, o3 = b2c.w;
#pragma unroll
            for (int k = 0; k < 8; ++k) {
                const float* f0 = (const float*)&w2f[0 + (k >> 2)];
                const float* f1 = (const float*)&w2f[2 + (k >> 2)];
                const float* f2 = (const float*)&w2f[4 + (k >> 2)];
                const float* f3 = (const float*)&w2f[6 + (k >> 2)];
                o0 += zq[k] * f0[k & 3]; o1 += zq[k] * f1[k & 3];
                o2 += zq[k] * f2[k & 3]; o3 += zq[k] * f3[k & 3];
            }
            nt_store4(orow + (size_t)r * EMBED, o0, o1, o2, o3);
        }
        // next iteration's phase A overwrites hcs/zf; same-wave DS ops are
        // processed in order, so no extra fence is needed beyond lds_fence().
    }
}

extern "C" void kernel_launch(void* const* d_in, const int* in_sizes, int n_in,
                              void* d_out, int out_size, void* d_ws, size_t ws_size,
                              hipStream_t stream) {
    const float* x  = (const float*)d_in[0];
    const float* W1 = (const float*)d_in[1];
    const float* b1 = (const float*)d_in[2];
    const float* qw = (const float*)d_in[3];
    const float* W2 = (const float*)d_in[4];
    const float* b2 = (const float*)d_in[5];
    float* out = (float*)d_out;

    hipLaunchKernelGGL(fused_kernel, dim3(65536 / (8 * ITERS) / 4), dim3(256),
                       0, stream, x, W1, b1, qw, W2, b2, out);
}

// Round 17
// 27.433 us; speedup vs baseline: 1.1912x; 1.1785x over previous
//
#include <hip/hip_runtime.h>

#define EMBED 256

typedef _Float16 h2v __attribute__((ext_vector_type(2)));
typedef float f4v __attribute__((ext_vector_type(4)));

__device__ inline float rfl(float v) {
    return __uint_as_float(__builtin_amdgcn_readfirstlane(__float_as_uint(v)));
}
template<int CTRL>
__device__ inline float dppf(float v) {
    return __int_as_float(__builtin_amdgcn_mov_dpp(__float_as_int(v), CTRL, 0xf, 0xf, true));
}
__device__ inline float2 unpk2(int u) {
    h2v h = __builtin_bit_cast(h2v, u);
    return make_float2((float)h.x, (float)h.y);
}
__device__ inline int pk2(float a, float b) {
    return __builtin_bit_cast(int, __builtin_amdgcn_cvt_pkrtz(a, b));
}
__device__ inline void lds_fence() {
    asm volatile("s_waitcnt lgkmcnt(0)" ::: "memory");
}
__device__ inline void nt_store4(float* p, float a, float b, float c, float d) {
    f4v v = {a, b, c, d};
    __builtin_nontemporal_store(v, (f4v*)p);
}

// ---- analytic-z compile-time term table (R7 derivation) ----
constexpr unsigned MQ[8] = {0x03,0x06,0x0C,0x18,0x30,0x60,0xC0,0x83};
constexpr unsigned TQ[8] = {0xAB,0xFD,0xFA,0xF5,0xEA,0xD5,0xAA,0x55};
constexpr unsigned AQ[8] = {0xFE,0x03,0x07,0x0F,0x1F,0x3F,0x7F,0xFF};

constexpr int popc8(unsigned x) {
    int c = 0;
    for (int i = 0; i < 8; ++i) c += (x >> i) & 1;
    return c;
}
struct Term { int q; unsigned S; unsigned M; float sgn; };
struct TermTab { Term t[64]; int n; };
constexpr TermTab make_terms() {
    TermTab tt{};
    int n = 0;
    for (int q = 0; q < 8; ++q)
        for (unsigned S = 0; S < 256; ++S) {
            if ((S & ~AQ[q]) != 0) continue;
            unsigned M = 0;
            for (int j = 0; j < 8; ++j) if ((S >> j) & 1) M ^= MQ[j];
            if ((M & ~TQ[q]) != 0) continue;
            const int tot = popc8(S) + popc8(M);   // always even
            tt.t[n].q = q; tt.t[n].S = S; tt.t[n].M = M;
            tt.t[n].sgn = ((tot >> 1) & 1) ? -1.0f : 1.0f;
            ++n;
        }
    tt.n = n;
    return tt;
}
constexpr TermTab TT = make_terms();
static_assert(TT.n == 60, "term count");

// Wave-independent fused kernel: each wave owns 8 samples end-to-end (one-shot).
// No __syncthreads; per-wave LDS scratch with same-wave lgkmcnt ordering.
// Phase A fully unrolled: all 16 x-loads in flight per wave (max read MLP).
__global__ __launch_bounds__(256) void fused_kernel(
    const float* __restrict__ x,    // (65536, 256)
    const float* __restrict__ W1,   // (8, 256)
    const float* __restrict__ b1,   // (8,)
    const float* __restrict__ qw,   // (2, 8)
    const float* __restrict__ W2,   // (256, 8)
    const float* __restrict__ b2,   // (256,)
    float* __restrict__ out)        // (65536, 256)
{
    const int tid  = threadIdx.x;
    const int lane = tid & 63;
    const int w    = tid >> 6;
    const int wid  = blockIdx.x * 4 + w;     // wave owns samples [wid*8, wid*8+8)

    __shared__ alignas(16) int   hcs[4][64];   // [wave][sl*8+q] packed f16 (cos,sin)
    __shared__ alignas(16) float zf[4][64];    // [wave][sl*8+q] z values

    // ---- phase-A constants ----
    float4 w1c[8];
#pragma unroll
    for (int q = 0; q < 8; ++q)
        w1c[q] = *(const float4*)(W1 + q * EMBED + 4 * lane);
    const int aq = (lane >> 1) & 7;            // valid for lane<16
    const float b1f = b1[aq] + qw[aq];         // + layer-1 RX angle (angles add)

    // gate trig (layer 2) for phase B
    float qc[8], qs[8];
#pragma unroll
    for (int j = 0; j < 8; ++j) {
        const float ph = qw[8 + j];
        qc[j] = rfl(__cosf(ph));
        qs[j] = rfl(__sinf(ph));
    }

    const bool s0 = lane & 1, s1 = lane & 2, s2 = lane & 4, s3 = lane & 8;

    // ---- phase A: theta = x.W1^T + b1 + qw[0]; pack (cos,sin) to LDS ----
    // Issue ALL 16 x row-loads first (full unroll) so the wave has maximum
    // memory-level parallelism before the first reduction consumes data.
#pragma unroll
    for (int step = 0; step < 4; ++step) {
        const int p = wid * 4 + step;          // pair index; samples 2p, 2p+1
        const float4 x0 = *(const float4*)(x + (size_t)p * 512 + 4 * lane);
        const float4 x1 = *(const float4*)(x + (size_t)p * 512 + 256 + 4 * lane);

        float vv[16];
#pragma unroll
        for (int q = 0; q < 8; ++q) {
            vv[2*q]   = x0.x*w1c[q].x + x0.y*w1c[q].y + x0.z*w1c[q].z + x0.w*w1c[q].w;
            vv[2*q+1] = x1.x*w1c[q].x + x1.y*w1c[q].y + x1.z*w1c[q].z + x1.w*w1c[q].w;
        }
#pragma unroll
        for (int i = 0; i < 8; ++i) {   // m=1 (DPP)
            float a = vv[2*i], b = vv[2*i+1];
            float keep = s0 ? b : a, send = s0 ? a : b;
            vv[i] = keep + dppf<0xB1>(send);
        }
#pragma unroll
        for (int i = 0; i < 4; ++i) {   // m=2 (DPP)
            float a = vv[2*i], b = vv[2*i+1];
            float keep = s1 ? b : a, send = s1 ? a : b;
            vv[i] = keep + dppf<0x4E>(send);
        }
#pragma unroll
        for (int i = 0; i < 2; ++i) {   // m=4
            float a = vv[2*i], b = vv[2*i+1];
            float keep = s2 ? b : a, send = s2 ? a : b;
            vv[i] = keep + __shfl_xor(send, 4, 64);
        }
        {                               // m=8
            float a = vv[0], b = vv[1];
            float keep = s3 ? b : a, send = s3 ? a : b;
            vv[0] = keep + __shfl_xor(send, 8, 64);
        }
        float r = vv[0];
        r += __shfl_xor(r, 16, 64);
        r += __shfl_xor(r, 32, 64);     // lane<16: dot for (q=lane>>1, par=lane&1)

        const float th = r + b1f;
        const int pk = pk2(__cosf(th), __sinf(th));
        if (lane < 16)
            hcs[w][(2 * step + (lane & 1)) * 8 + (lane >> 1)] = pk;
    }
    lds_fence();

    // ---- phase B: lane (sl,q) accumulates q's terms for sample sl ----
    const int sl = lane >> 3;
    const int q  = lane & 7;
    const int4 ua = *(const int4*)&hcs[w][sl * 8];
    const int4 ub = *(const int4*)&hcs[w][sl * 8 + 4];
    float u[8], v[8];
#define UNPK(U, Q) do { float2 f = unpk2(U); u[Q] = f.x; v[Q] = f.y; } while (0)
    UNPK(ua.x, 0); UNPK(ua.y, 1); UNPK(ua.z, 2); UNPK(ua.w, 3);
    UNPK(ub.x, 4); UNPK(ub.y, 5); UNPK(ub.z, 6); UNPK(ub.w, 7);
#undef UNPK

    float acc = 0.0f, psum = 0.0f;
#pragma unroll
    for (int t = 0; t < 60; ++t) {
        const int qt = TT.t[t].q;
        const unsigned S = TT.t[t].S, M = TT.t[t].M;
        float c = TT.t[t].sgn;
#pragma unroll
        for (int j = 0; j < 8; ++j)
            if ((AQ[qt] >> j) & 1) c *= ((S >> j) & 1) ? qs[j] : qc[j];
#pragma unroll
        for (int i = 0; i < 8; ++i)
            if ((TQ[qt] >> i) & 1) c *= ((M >> i) & 1) ? v[i] : u[i];
        psum += c;
        const bool qend = (t == 59) || (TT.t[t + 1].q != qt);
        if (qend) { acc += (q == qt) ? psum : 0.0f; psum = 0.0f; }
    }
    zf[w][lane] = acc;
    lds_fence();

    // ---- phase C: out = z.W2^T + b2, 8 coalesced rows per wave ----
    // W2 rows for e = 4*lane..4*lane+3 are 128 B contiguous: load as 8 float4.
    float4 w2f[8];
#pragma unroll
    for (int j = 0; j < 8; ++j)
        w2f[j] = *(const float4*)(W2 + (size_t)lane * 32 + 4 * j);
    const float4 b2c = *(const float4*)(b2 + 4 * lane);

    float* orow = out + (size_t)(wid * 8) * EMBED + 4 * lane;
#pragma unroll
    for (int r = 0; r < 8; ++r) {
        const float4 za = *(const float4*)&zf[w][r * 8];
        const float4 zb = *(const float4*)&zf[w][r * 8 + 4];
        const float zq[8] = {za.x, za.y, za.z, za.w, zb.x, zb.y, zb.z, zb.w};
        float o0 = b2c.x, o1 = b2c.y, o2 = b2c.z, o3 = b2c.w;
#pragma unroll
        for (int k = 0; k < 8; ++k) {
            // w2r[j][k] = W2[(4*lane+j)*8+k] = w2f[j*2 + (k>>2)][k&3]
            const float* f0 = (const float*)&w2f[0 + (k >> 2)];
            const float* f1 = (const float*)&w2f[2 + (k >> 2)];
            const float* f2 = (const float*)&w2f[4 + (k >> 2)];
            const float* f3 = (const float*)&w2f[6 + (k >> 2)];
            o0 += zq[k] * f0[k & 3]; o1 += zq[k] * f1[k & 3];
            o2 += zq[k] * f2[k & 3]; o3 += zq[k] * f3[k & 3];
        }
        nt_store4(orow + (size_t)r * EMBED, o0, o1, o2, o3);
    }
}

extern "C" void kernel_launch(void* const* d_in, const int* in_sizes, int n_in,
                              void* d_out, int out_size, void* d_ws, size_t ws_size,
                              hipStream_t stream) {
    const float* x  = (const float*)d_in[0];
    const float* W1 = (const float*)d_in[1];
    const float* b1 = (const float*)d_in[2];
    const float* qw = (const float*)d_in[3];
    const float* W2 = (const float*)d_in[4];
    const float* b2 = (const float*)d_in[5];
    float* out = (float*)d_out;

    hipLaunchKernelGGL(fused_kernel, dim3(2048), dim3(256), 0, stream,
                       x, W1, b1, qw, W2, b2, out);
}